// Round 17
// baseline (446.866 us; speedup 1.0000x reference)
//
#include <hip/hip_runtime.h>

typedef __attribute__((ext_vector_type(8))) unsigned short us8;
typedef __attribute__((ext_vector_type(8))) __bf16 bf16x8;
typedef __attribute__((ext_vector_type(4))) float f32x4;

#define RS   1048   // tile d2-row stride in shorts
#define D3S  40     // tile d3 stride in shorts (32 c + 8 pad)
#define XT_SHORTS 28672  // padded tile: 3584 16B-slots
#define WELEMS 165888    // 3*64*32*27 weight elements (one bf16 plane)
#define W2_BYTES  663552
#define X2_BYTES  ((size_t)1248 * XT_SHORTS * 2)   // 71,565,312

// Reference semantics (derived, certified by prior session):
//   out[b,o,d0,d1,d2,d3] = bias[o] + sum_{i<3, c<32, k1,k2,k3}
//       X(b, r=(d0+i)*32+c ; d1+k1-1, d2+k2-1, d3+k3-1) * w[i,o,c,k1,k2,k3]
//   where X reads x[b, ci=r/26, pf=r%26-1, ...], zero if pf or spatial idx out of [0,24).
//
// Numerics: 1-term bf16 (r12-verified; analysis absmax ~9e-3, harness artifact
// 0.03125 dominates). Fallback kernel stays 2-term.
//
// Round-17: 12-wave M-split for 3 waves/SIMD. r16 left VGPR=88 (80+ regs of
// headroom/wave). Extending the r15 decomposition: 12 waves of M=96 x N=32
// (acc[6][2]=48 regs) at launch_bounds(768,3) -> 3 waves/SIMD, reg cap 170.
// LDS A-read traffic UNCHANGED (12x54 = 648 reads/stage = r15/16's 8x81);
// MFMA work conserved (12x108 = 1296). The 3rd co-resident wave hides the
// ~3.6K cyc/stage of weight-L2/DMA/barrier skew still exposed at 2 waves/SIMD
// (stage 14.1K vs LDS-pipe floor ~10.5K). Stagger generalizes to 3 phases:
// tp = (it + 3*(wv>>2)) % 9 — one wave per phase per SIMD.

__device__ __forceinline__ unsigned short f2bf(float f) {
    unsigned int u = __builtin_bit_cast(unsigned int, f);
    u += 0x7FFFu + ((u >> 16) & 1u);
    return (unsigned short)(u >> 16);
}

__device__ __forceinline__ void f2bf2(float f, unsigned short& h, unsigned short& l) {
    h = f2bf(f);
    float hf = __builtin_bit_cast(float, (unsigned int)h << 16);
    l = f2bf(f - hf);
}

__device__ __forceinline__ void wconv_body(int e, const float* __restrict__ w,
                                           unsigned short* __restrict__ w2) {
    int ci  = e & 31;
    int o   = (e >> 5) & 63;
    int tap = e >> 11;
    int k3 = tap % 3;
    int k2 = (tap / 3) % 3;
    int k1 = (tap / 9) % 3;
    int i  = tap / 27;
    int src = ((i * 64 + o) * 32 + ci) * 27 + (k1 * 9 + k2 * 3 + k3);
    unsigned short h, l;
    f2bf2(w[src], h, l);
    w2[e]          = h;
    w2[e + WELEMS] = l;
}

// standalone wconv (fallback path only)
__global__ void wconv_kernel(const float* __restrict__ w, unsigned short* __restrict__ w2) {
    wconv_body(blockIdx.x * 256 + threadIdx.x, w, w2);
}

// Merged prep: blocks [0,648) = wconv; blocks [648,1896) = xprep tile build.
// x (fp32) -> x2 bf16 tiles [b][m=0..25][d1=0..23][XT_SHORTS], borders zero.
// Tile short index S = (d2+1)*RS + (d3+1)*D3S + c  (input coords d2,d3 in [0,24)).
__global__ __launch_bounds__(256, 2)
void prep_kernel(const float* __restrict__ x, const float* __restrict__ w,
                 unsigned short* __restrict__ w2, unsigned short* __restrict__ x2) {
    __shared__ __align__(16) unsigned short xt[XT_SHORTS];   // 57,344 B
    const int tid  = threadIdx.x;

    if (blockIdx.x < 648) {
        wconv_body(blockIdx.x * 256 + tid, w, w2);
        return;
    }

    const int lane = tid & 63;
    const int wv   = tid >> 6;
    const int T  = blockIdx.x - 648;      // (b*26 + m)*24 + d1, 1248 blocks
    const int d1 = T % 24;
    const int m  = (T / 24) % 26;
    const int b  = T / 624;

    for (int e = tid * 8; e < XT_SHORTS; e += 2048)
        *(us8*)&xt[e] = (us8)0;
    __syncthreads();

    const float* xb_b = x + (size_t)b * 10616832;
    const int cbase = wv * 8;
    int off8[8]; float msk8[8];
    #pragma unroll
    for (int cc = 0; cc < 8; ++cc) {
        int r  = 32 * m + cbase + cc;
        int ci = r / 26;
        int pf = r - ci * 26 - 1;
        bool valid = ((unsigned)pf < 24u);
        off8[cc] = valid ? (ci * 331776 + pf * 13824 + d1 * 576) : 0;
        msk8[cc] = valid ? 1.0f : 0.0f;
    }
    #pragma unroll
    for (int jj = 0; jj < 3; ++jj) {
        int f4 = lane + 64 * jj;
        if (f4 < 144) {
            int d2  = f4 / 6;
            int d3c = f4 - d2 * 6;
            int pos = d2 * 24 + d3c * 4;
            f32x4 v[8];
            #pragma unroll
            for (int cc = 0; cc < 8; ++cc)
                v[cc] = *(const f32x4*)(xb_b + off8[cc] + pos);
            const int le = (d2 + 1) * RS + (d3c * 4 + 1) * D3S + cbase;
            #pragma unroll
            for (int k = 0; k < 4; ++k) {
                us8 hv;
                #pragma unroll
                for (int cc = 0; cc < 8; ++cc)
                    hv[cc] = f2bf(v[cc][k] * msk8[cc]);
                *(us8*)&xt[le + k * D3S] = hv;
            }
        }
    }
    __syncthreads();

    unsigned short* tile = x2 + (size_t)T * XT_SHORTS;
    for (int e = tid * 8; e < XT_SHORTS; e += 2048)
        *(us8*)&tile[e] = *(const us8*)&xt[e];   // coalesced 16B/lane
}

typedef __attribute__((address_space(1))) const unsigned short gus_t;
typedef __attribute__((address_space(3))) unsigned short lus_t;

__global__ __launch_bounds__(768, 3)
void conv4d_dma_kernel(const unsigned short* __restrict__ x2,
                       const unsigned short* __restrict__ w2,
                       const float* __restrict__ bias, float* __restrict__ out) {
    __shared__ __align__(16) unsigned short xa[2][XT_SHORTS];   // 114,688 B
    __shared__ __align__(16) float tb[12][320];                 //  15,360 B

    const int tid  = threadIdx.x;
    const int lane = tid & 63;
    const int wv   = tid >> 6;          // 12 waves: mg = wv>>1 (M-sixth), og = wv&1 (o-half)
    const int n    = lane & 15;
    const int q    = lane >> 4;
    const int og   = wv & 1;
    const int mg   = wv >> 1;           // 0..5, 96 rows each
    const int ph   = wv >> 2;           // 0..2: tap phase; one per SIMD

    int bid = blockIdx.x;
    bid = (bid & 7) * 144 + (bid >> 3);      // XCD swizzle (1152 = 8*144, bijective)
    const int d1 = bid % 24;
    const int d0 = (bid / 24) % 24;
    const int b  = bid / 576;

    int abase[6];
    #pragma unroll
    for (int t = 0; t < 6; ++t) {
        int mflat = (mg * 6 + t) * 16 + n;
        int d2o = mflat / 24;
        int d3o = mflat - d2o * 24;
        abase[t] = d2o * RS + d3o * D3S + q * 8;
    }

    f32x4 acc[6][2];                    // 48 regs/wave: fits the 3-wave/SIMD cap
    #pragma unroll
    for (int t = 0; t < 6; ++t)
        #pragma unroll
        for (int nt = 0; nt < 2; ++nt)
            acc[t][nt] = (f32x4)0.0f;

    const int k1lo = (d1 == 0) ? 1 : 0;
    const int k1hi = (d1 == 23) ? 1 : 2;
    const int nk = k1hi - k1lo + 1;
    const int ns = 3 * nk;

    // stage s -> tile (b, m=d0+s/nk, d1in=d1+k1lo+s%nk-1); linear 57,344B DMA.
    // 56 wave-insts total: waves 0-7 issue 5, waves 8-11 issue 4 (8*5+4*4=56).
    const int nj    = (wv < 8) ? 5 : 4;
    const int jbase = (wv < 8) ? wv * 5 : 40 + (wv - 8) * 4;   // 64-slot units
    auto DMA = [&](int s, int bufi) {
        const int ik  = s / nk;
        const int k1c = k1lo + (s - ik * nk);
        const int d1t = d1 + k1c - 1;
        const unsigned short* tp = x2 + (size_t)(((b * 26 + (d0 + ik)) * 24) + d1t) * XT_SHORTS;
        #pragma unroll
        for (int j = 0; j < 5; ++j) {
            if (j < nj) {               // wave-uniform guard
                const int slot = (jbase + j) * 64;
                __builtin_amdgcn_global_load_lds((gus_t*)(tp + slot * 8 + lane * 8),
                                                 (lus_t*)&xa[bufi][slot * 8], 16, 0, 0);
            }
        }
    };

    // prologue: stage 0's tile
    DMA(0, 0);
    asm volatile("s_waitcnt vmcnt(0)" ::: "memory");
    __builtin_amdgcn_s_barrier();
    asm volatile("" ::: "memory");

    for (int s = 0; s < ns; ++s) {
        const unsigned short* xbuf = &xa[s & 1][0];
        const int ik  = s / nk;
        const int k1c = k1lo + (s - ik * nk);
        const unsigned short* wsliceH = w2 + (size_t)((ik * 3 + k1c) * 9) * 2048;

        // rotating 3-deep weight buffers, indexed by ITERATION (static regs);
        // the tap identity tp only changes addresses. This wave's o-half.
        bf16x8 wbh[3][2];
        auto LW = [&](int tp, int rb) {
            #pragma unroll
            for (int nt = 0; nt < 2; ++nt) {
                const int wo = (tp * 64 + (og * 2 + nt) * 16 + n) * 32 + q * 8;
                wbh[rb][nt] = __builtin_bit_cast(bf16x8, *(const us8*)(wsliceH + wo));
            }
        };

        // weight preloads for the first three iterations' taps, then the DMA
        LW(3 * ph, 0); LW(3 * ph + 1, 1); LW(3 * ph + 2, 2);
        __builtin_amdgcn_sched_barrier(0);
        if (s + 1 < ns) DMA(s + 1, (s + 1) & 1);
        __builtin_amdgcn_sched_barrier(0);

        __builtin_amdgcn_s_setprio(1);
        #pragma unroll
        for (int it = 0; it < 9; ++it) {
            const int rb = it % 3;                    // static per unrolled copy
            int tp = it + 3 * ph; if (tp >= 9) tp -= 9;   // wave-uniform
            const int toff = (tp / 3) * RS + (tp % 3) * D3S;
            #pragma unroll
            for (int t = 0; t < 6; ++t) {
                const bf16x8 ah = __builtin_bit_cast(bf16x8, *(const us8*)(&xbuf[abase[t] + toff]));
                #pragma unroll
                for (int nt = 0; nt < 2; ++nt)
                    acc[t][nt] = __builtin_amdgcn_mfma_f32_16x16x32_bf16(ah, wbh[rb][nt], acc[t][nt], 0, 0, 0);
            }
            if (it + 3 < 9) {
                int tn = it + 3 + 3 * ph; if (tn >= 9) tn -= 9;
                LW(tn, rb);
            }
        }
        __builtin_amdgcn_s_setprio(0);

        // stage boundary — skipped after the last stage (no DMA in flight; the
        // epilogue never reads xa, and tb is per-wave)
        if (s + 1 < ns) {
            asm volatile("s_waitcnt vmcnt(0)" ::: "memory");
            __builtin_amdgcn_s_barrier();
            asm volatile("" ::: "memory");
        }
    }

    // epilogue, interp A (col=o, row=m — certified). tb per-wave: lgkmcnt only.
    const int o4 = lane >> 2;
    const int mc = lane & 3;
    float* tbw = tb[wv];
    const size_t plane = (size_t)d0 * 24 + d1;
    #pragma unroll
    for (int t = 0; t < 6; ++t) {
        #pragma unroll
        for (int nt = 0; nt < 2; ++nt) {
            asm volatile("" ::: "memory");
            *(f32x4*)&tbw[n * 20 + q * 4] = acc[t][nt];   // tb[o=n][m=q*4+r]
            asm volatile("s_waitcnt lgkmcnt(0)" ::: "memory");
            f32x4 vv = *(const f32x4*)&tbw[o4 * 20 + mc * 4];
            const int o = (og * 2 + nt) * 16 + o4;
            vv += bias[o];
            size_t off = ((size_t)(b * 64 + o) * 576 + plane) * 576
                       + (size_t)((mg * 6 + t) * 16 + mc * 4);
            __builtin_nontemporal_store(vv, (f32x4*)(out + off));
        }
    }
}

// ---- fallback (round-6 verified kernel, 2-term; used only if ws_size small) ----
__global__ __launch_bounds__(256, 1)
void conv4d_kernel(const float* __restrict__ x, const unsigned short* __restrict__ w2,
                   const float* __restrict__ bias, float* __restrict__ out) {
    __shared__ __align__(16) unsigned short xsh[27232];
    __shared__ __align__(16) float tb[4][320];

    const int tid  = threadIdx.x;
    const int lane = tid & 63;
    const int wv   = tid >> 6;
    const int n    = lane & 15;
    const int q    = lane >> 4;

    int bid = blockIdx.x;
    bid = (bid & 7) * 144 + (bid >> 3);
    const int d1 = bid % 24;
    const int d0 = (bid / 24) % 24;
    const int b  = bid / 576;

    for (int e = tid * 8; e < 27232; e += 2048) *(us8*)&xsh[e] = (us8)0;

    int abase[9];
    #pragma unroll
    for (int t = 0; t < 9; ++t) {
        int mflat = (wv * 9 + t) * 16 + n;
        int d2o = mflat / 24;
        int d3o = mflat - d2o * 24;
        abase[t] = d2o * RS + d3o * D3S + q * 8;
    }

    f32x4 acc[9][4];
    #pragma unroll
    for (int t = 0; t < 9; ++t)
        #pragma unroll
        for (int nt = 0; nt < 4; ++nt)
            acc[t][nt] = (f32x4)0.0f;

    const float* xb_b = x + (size_t)b * 10616832;
    const int cbase = wv * 8;
    const int k1lo = (d1 == 0) ? 1 : 0;
    const int k1hi = (d1 == 23) ? 1 : 2;
    const int nk = k1hi - k1lo + 1;
    const int ns = 3 * nk;

    f32x4 v[3][8];
    float mskC[8], mskN[8];
    {
        const int d1in = d1 + k1lo - 1;
        int off0[8];
        #pragma unroll
        for (int cc = 0; cc < 8; ++cc) {
            int r  = d0 * 32 + cbase + cc;
            int ci = r / 26;
            int pf = r - ci * 26 - 1;
            bool valid = ((unsigned)pf < 24u);
            off0[cc] = valid ? (ci * 331776 + pf * 13824 + d1in * 576) : 0;
            mskC[cc] = valid ? 1.0f : 0.0f;
        }
        #pragma unroll
        for (int jj = 0; jj < 3; ++jj) {
            int f4 = lane + 64 * jj;
            if (f4 < 144) {
                int d2  = f4 / 6;
                int d3c = f4 - d2 * 6;
                int pos = d2 * 24 + d3c * 4;
                #pragma unroll
                for (int cc = 0; cc < 8; ++cc)
                    v[jj][cc] = *(const f32x4*)(xb_b + off0[cc] + pos);
            }
        }
    }

    for (int s = 0; s < ns; ++s) {
        #pragma unroll
        for (int jj = 0; jj < 3; ++jj) {
            int f4 = lane + 64 * jj;
            if (f4 < 144) {
                int d2  = f4 / 6;
                int d3c = f4 - d2 * 6;
                const int le = (d2 + 1) * RS + (d3c * 4 + 1) * D3S + cbase;
                #pragma unroll
                for (int k = 0; k < 4; ++k) {
                    us8 hv;
                    #pragma unroll
                    for (int cc = 0; cc < 8; ++cc)
                        hv[cc] = f2bf(v[jj][cc][k] * mskC[cc]);
                    *(us8*)&xsh[le + k * D3S] = hv;
                }
            }
        }
        if (s + 1 < ns) {
            const int sn   = s + 1;
            const int i_n  = sn / nk;
            const int k1_n = k1lo + (sn - i_n * nk);
            const int d1in = d1 + k1_n - 1;
            int offn[8];
            #pragma unroll
            for (int cc = 0; cc < 8; ++cc) {
                int r  = (d0 + i_n) * 32 + cbase + cc;
                int ci = r / 26;
                int pf = r - ci * 26 - 1;
                bool valid = ((unsigned)pf < 24u);
                offn[cc] = valid ? (ci * 331776 + pf * 13824 + d1in * 576) : 0;
                mskN[cc] = valid ? 1.0f : 0.0f;
            }
            #pragma unroll
            for (int jj = 0; jj < 3; ++jj) {
                int f4 = lane + 64 * jj;
                if (f4 < 144) {
                    int d2  = f4 / 6;
                    int d3c = f4 - d2 * 6;
                    int pos = d2 * 24 + d3c * 4;
                    #pragma unroll
                    for (int cc = 0; cc < 8; ++cc)
                        v[jj][cc] = *(const f32x4*)(xb_b + offn[cc] + pos);
                }
            }
            #pragma unroll
            for (int cc = 0; cc < 8; ++cc) mskC[cc] = mskN[cc];
        }
        asm volatile("s_waitcnt lgkmcnt(0)" ::: "memory");
        __builtin_amdgcn_s_barrier();
        asm volatile("" ::: "memory");

        const int ik  = s / nk;
        const int k1c = k1lo + (s - ik * nk);
        const unsigned short* wsliceH = w2 + (size_t)((ik * 3 + k1c) * 9) * 2048;
        const unsigned short* wsliceL = wsliceH + WELEMS;
        __builtin_amdgcn_s_setprio(1);
        #pragma unroll
        for (int k2 = 0; k2 < 3; ++k2) {
            #pragma unroll
            for (int k3 = 0; k3 < 3; ++k3) {
                const int tap = k2 * 3 + k3;
                bf16x8 bh[4], bl[4];
                #pragma unroll
                for (int nt = 0; nt < 4; ++nt) {
                    const int wo = (tap * 64 + nt * 16 + n) * 32 + q * 8;
                    bh[nt] = __builtin_bit_cast(bf16x8, *(const us8*)(wsliceH + wo));
                    bl[nt] = __builtin_bit_cast(bf16x8, *(const us8*)(wsliceL + wo));
                }
                const int toff = k2 * RS + k3 * D3S;
                #pragma unroll
                for (int t = 0; t < 9; ++t) {
                    const bf16x8 ah = __builtin_bit_cast(bf16x8, *(const us8*)(&xsh[abase[t] + toff]));
                    #pragma unroll
                    for (int nt = 0; nt < 4; ++nt) {
                        acc[t][nt] = __builtin_amdgcn_mfma_f32_16x16x32_bf16(ah, bh[nt], acc[t][nt], 0, 0, 0);
                        acc[t][nt] = __builtin_amdgcn_mfma_f32_16x16x32_bf16(ah, bl[nt], acc[t][nt], 0, 0, 0);
                    }
                }
            }
        }
        __builtin_amdgcn_s_setprio(0);
        asm volatile("" ::: "memory");
        __builtin_amdgcn_s_barrier();
        asm volatile("" ::: "memory");
    }

    const int o4 = lane >> 2;
    const int mc = lane & 3;
    float* tbw = tb[wv];
    const size_t plane = (size_t)d0 * 24 + d1;
    #pragma unroll
    for (int t = 0; t < 9; ++t) {
        #pragma unroll
        for (int nt = 0; nt < 4; ++nt) {
            asm volatile("" ::: "memory");
            *(f32x4*)&tbw[n * 20 + q * 4] = acc[t][nt];
            asm volatile("s_waitcnt lgkmcnt(0)" ::: "memory");
            f32x4 vv = *(const f32x4*)&tbw[o4 * 20 + mc * 4];
            const int o = nt * 16 + o4;
            vv += bias[o];
            size_t off = ((size_t)(b * 64 + o) * 576 + plane) * 576
                       + (size_t)((wv * 9 + t) * 16 + mc * 4);
            __builtin_nontemporal_store(vv, (f32x4*)(out + off));
        }
    }
}

extern "C" void kernel_launch(void* const* d_in, const int* in_sizes, int n_in,
                              void* d_out, int out_size, void* d_ws, size_t ws_size,
                              hipStream_t stream) {
    const float* x    = (const float*)d_in[0];
    const float* w    = (const float*)d_in[1];
    const float* bias = (const float*)d_in[2];
    float* out        = (float*)d_out;
    unsigned short* w2 = (unsigned short*)d_ws;

    if (ws_size >= W2_BYTES + X2_BYTES) {
        unsigned short* x2 = (unsigned short*)((char*)d_ws + W2_BYTES);
        hipLaunchKernelGGL(prep_kernel, dim3(648 + 1248), dim3(256), 0, stream,
                           x, w, w2, x2);
        hipLaunchKernelGGL(conv4d_dma_kernel, dim3(1152), dim3(768), 0, stream,
                           x2, w2, bias, out);
    } else {
        hipLaunchKernelGGL(wconv_kernel, dim3(648), dim3(256), 0, stream, w, w2);
        hipLaunchKernelGGL(conv4d_kernel, dim3(1152), dim3(256), 0, stream,
                           x, w2, bias, out);
    }
}

// Round 18
// 423.667 us; speedup vs baseline: 1.0548x; 1.0548x over previous
//
#include <hip/hip_runtime.h>

typedef __attribute__((ext_vector_type(8))) unsigned short us8;
typedef __attribute__((ext_vector_type(8))) __bf16 bf16x8;
typedef __attribute__((ext_vector_type(4))) float f32x4;

#define RS   1048   // tile d2-row stride in shorts
#define D3S  40     // tile d3 stride in shorts (32 c + 8 pad)
#define XT_SHORTS 28672  // padded tile: 3584 16B-slots
#define WELEMS 165888    // 3*64*32*27 weight elements (one bf16 plane)
#define W2_BYTES  663552
#define X2_BYTES  ((size_t)1248 * XT_SHORTS * 2)   // 71,565,312

// Reference semantics (derived, certified by prior session):
//   out[b,o,d0,d1,d2,d3] = bias[o] + sum_{i<3, c<32, k1,k2,k3}
//       X(b, r=(d0+i)*32+c ; d1+k1-1, d2+k2-1, d3+k3-1) * w[i,o,c,k1,k2,k3]
//   where X reads x[b, ci=r/26, pf=r%26-1, ...], zero if pf or spatial idx out of [0,24).
//
// Numerics: 1-term bf16 (r12-verified; analysis absmax ~9e-3, harness artifact
// 0.03125 dominates). Fallback kernel stays 2-term.
//
// FINAL (r18 = r16, the session optimum at 431.8us total / 232us conv):
// 8 waves of M=144 x N=32 (acc[9][2]=72 regs) at launch_bounds(512,2) ->
// 2 waves/SIMD without spill, double-buffered tile DMA via global_load_lds,
// anti-phase tap stagger (SIMD-mates traverse taps in opposite orders so the
// LDS pipe and matrix pipe co-issue), 3-deep weight register rotation.
// Closed doors (measured): schedule reorders (r6/r11/r13), >=2-wave N=64
// (reg-cliff spill, r4/r8/r9/r10), 3 waves/SIMD (r17 regression), P/C (r9/r10),
// 2-blocks/CU (r8 L2 thrash). Bank-conflict counter = inherent b128 multi-phase
// (4.2 cyc/read = m134's 12 vs 8 min; all access patterns bank-balanced).

__device__ __forceinline__ unsigned short f2bf(float f) {
    unsigned int u = __builtin_bit_cast(unsigned int, f);
    u += 0x7FFFu + ((u >> 16) & 1u);
    return (unsigned short)(u >> 16);
}

__device__ __forceinline__ void f2bf2(float f, unsigned short& h, unsigned short& l) {
    h = f2bf(f);
    float hf = __builtin_bit_cast(float, (unsigned int)h << 16);
    l = f2bf(f - hf);
}

__device__ __forceinline__ void wconv_body(int e, const float* __restrict__ w,
                                           unsigned short* __restrict__ w2) {
    int ci  = e & 31;
    int o   = (e >> 5) & 63;
    int tap = e >> 11;
    int k3 = tap % 3;
    int k2 = (tap / 3) % 3;
    int k1 = (tap / 9) % 3;
    int i  = tap / 27;
    int src = ((i * 64 + o) * 32 + ci) * 27 + (k1 * 9 + k2 * 3 + k3);
    unsigned short h, l;
    f2bf2(w[src], h, l);
    w2[e]          = h;
    w2[e + WELEMS] = l;
}

// standalone wconv (fallback path only)
__global__ void wconv_kernel(const float* __restrict__ w, unsigned short* __restrict__ w2) {
    wconv_body(blockIdx.x * 256 + threadIdx.x, w, w2);
}

// Merged prep: blocks [0,648) = wconv; blocks [648,1896) = xprep tile build.
// x (fp32) -> x2 bf16 tiles [b][m=0..25][d1=0..23][XT_SHORTS], borders zero.
// Tile short index S = (d2+1)*RS + (d3+1)*D3S + c  (input coords d2,d3 in [0,24)).
__global__ __launch_bounds__(256, 2)
void prep_kernel(const float* __restrict__ x, const float* __restrict__ w,
                 unsigned short* __restrict__ w2, unsigned short* __restrict__ x2) {
    __shared__ __align__(16) unsigned short xt[XT_SHORTS];   // 57,344 B
    const int tid  = threadIdx.x;

    if (blockIdx.x < 648) {
        wconv_body(blockIdx.x * 256 + tid, w, w2);
        return;
    }

    const int lane = tid & 63;
    const int wv   = tid >> 6;
    const int T  = blockIdx.x - 648;      // (b*26 + m)*24 + d1, 1248 blocks
    const int d1 = T % 24;
    const int m  = (T / 24) % 26;
    const int b  = T / 624;

    for (int e = tid * 8; e < XT_SHORTS; e += 2048)
        *(us8*)&xt[e] = (us8)0;
    __syncthreads();

    const float* xb_b = x + (size_t)b * 10616832;
    const int cbase = wv * 8;
    int off8[8]; float msk8[8];
    #pragma unroll
    for (int cc = 0; cc < 8; ++cc) {
        int r  = 32 * m + cbase + cc;
        int ci = r / 26;
        int pf = r - ci * 26 - 1;
        bool valid = ((unsigned)pf < 24u);
        off8[cc] = valid ? (ci * 331776 + pf * 13824 + d1 * 576) : 0;
        msk8[cc] = valid ? 1.0f : 0.0f;
    }
    #pragma unroll
    for (int jj = 0; jj < 3; ++jj) {
        int f4 = lane + 64 * jj;
        if (f4 < 144) {
            int d2  = f4 / 6;
            int d3c = f4 - d2 * 6;
            int pos = d2 * 24 + d3c * 4;
            f32x4 v[8];
            #pragma unroll
            for (int cc = 0; cc < 8; ++cc)
                v[cc] = *(const f32x4*)(xb_b + off8[cc] + pos);
            const int le = (d2 + 1) * RS + (d3c * 4 + 1) * D3S + cbase;
            #pragma unroll
            for (int k = 0; k < 4; ++k) {
                us8 hv;
                #pragma unroll
                for (int cc = 0; cc < 8; ++cc)
                    hv[cc] = f2bf(v[cc][k] * msk8[cc]);
                *(us8*)&xt[le + k * D3S] = hv;
            }
        }
    }
    __syncthreads();

    unsigned short* tile = x2 + (size_t)T * XT_SHORTS;
    for (int e = tid * 8; e < XT_SHORTS; e += 2048)
        *(us8*)&tile[e] = *(const us8*)&xt[e];   // coalesced 16B/lane
}

typedef __attribute__((address_space(1))) const unsigned short gus_t;
typedef __attribute__((address_space(3))) unsigned short lus_t;

__global__ __launch_bounds__(512, 2)
void conv4d_dma_kernel(const unsigned short* __restrict__ x2,
                       const unsigned short* __restrict__ w2,
                       const float* __restrict__ bias, float* __restrict__ out) {
    __shared__ __align__(16) unsigned short xa[2][XT_SHORTS];   // 114,688 B
    __shared__ __align__(16) float tb[8][320];                  //  10,240 B

    const int tid  = threadIdx.x;
    const int lane = tid & 63;
    const int wv   = tid >> 6;          // 8 waves: mg = wv>>1 (M-quarter), og = wv&1 (o-half)
    const int n    = lane & 15;
    const int q    = lane >> 4;
    const int og   = wv & 1;
    const int mg   = wv >> 1;
    const int rev  = (wv >> 2) & 1;     // SIMD-mates (wv, wv+4) get opposite tap orders

    int bid = blockIdx.x;
    bid = (bid & 7) * 144 + (bid >> 3);      // XCD swizzle (1152 = 8*144, bijective)
    const int d1 = bid % 24;
    const int d0 = (bid / 24) % 24;
    const int b  = bid / 576;

    int abase[9];
    #pragma unroll
    for (int t = 0; t < 9; ++t) {
        int mflat = (mg * 9 + t) * 16 + n;
        int d2o = mflat / 24;
        int d3o = mflat - d2o * 24;
        abase[t] = d2o * RS + d3o * D3S + q * 8;
    }

    f32x4 acc[9][2];                    // 72 regs/wave: fits the 2-wave/SIMD cap
    #pragma unroll
    for (int t = 0; t < 9; ++t)
        #pragma unroll
        for (int nt = 0; nt < 2; ++nt)
            acc[t][nt] = (f32x4)0.0f;

    const int k1lo = (d1 == 0) ? 1 : 0;
    const int k1hi = (d1 == 23) ? 1 : 2;
    const int nk = k1hi - k1lo + 1;
    const int ns = 3 * nk;

    // stage s -> tile (b, m=d0+s/nk, d1in=d1+k1lo+s%nk-1); linear 57,344B DMA,
    // 7 insts per wave x 8 waves = 3584 16B slots
    auto DMA = [&](int s, int bufi) {
        const int ik  = s / nk;
        const int k1c = k1lo + (s - ik * nk);
        const int d1t = d1 + k1c - 1;
        const unsigned short* tp = x2 + (size_t)(((b * 26 + (d0 + ik)) * 24) + d1t) * XT_SHORTS;
        #pragma unroll
        for (int j = 0; j < 7; ++j) {
            const int slot = wv * 448 + j * 64;   // 16B slots; wave-uniform base
            __builtin_amdgcn_global_load_lds((gus_t*)(tp + slot * 8 + lane * 8),
                                             (lus_t*)&xa[bufi][slot * 8], 16, 0, 0);
        }
    };

    // prologue: stage 0's tile
    DMA(0, 0);
    asm volatile("s_waitcnt vmcnt(0)" ::: "memory");
    __builtin_amdgcn_s_barrier();
    asm volatile("" ::: "memory");

    for (int s = 0; s < ns; ++s) {
        const unsigned short* xbuf = &xa[s & 1][0];
        const int ik  = s / nk;
        const int k1c = k1lo + (s - ik * nk);
        const unsigned short* wsliceH = w2 + (size_t)((ik * 3 + k1c) * 9) * 2048;

        // rotating 3-deep weight buffers, indexed by ITERATION (static regs);
        // the tap identity tp only changes addresses. This wave's o-half.
        bf16x8 wbh[3][2];
        auto LW = [&](int tp, int rb) {
            #pragma unroll
            for (int nt = 0; nt < 2; ++nt) {
                const int wo = (tp * 64 + (og * 2 + nt) * 16 + n) * 32 + q * 8;
                wbh[rb][nt] = __builtin_bit_cast(bf16x8, *(const us8*)(wsliceH + wo));
            }
        };

        // weight preloads for the first three iterations' taps, then the DMA
        LW(rev ? 8 : 0, 0); LW(rev ? 7 : 1, 1); LW(rev ? 6 : 2, 2);
        __builtin_amdgcn_sched_barrier(0);
        if (s + 1 < ns) DMA(s + 1, (s + 1) & 1);
        __builtin_amdgcn_sched_barrier(0);

        __builtin_amdgcn_s_setprio(1);
        #pragma unroll
        for (int it = 0; it < 9; ++it) {
            const int rb = it % 3;                    // static per unrolled copy
            const int tp = rev ? (8 - it) : it;       // wave-uniform select
            const int toff = (tp / 3) * RS + (tp % 3) * D3S;
            #pragma unroll
            for (int t = 0; t < 9; ++t) {
                const bf16x8 ah = __builtin_bit_cast(bf16x8, *(const us8*)(&xbuf[abase[t] + toff]));
                #pragma unroll
                for (int nt = 0; nt < 2; ++nt)
                    acc[t][nt] = __builtin_amdgcn_mfma_f32_16x16x32_bf16(ah, wbh[rb][nt], acc[t][nt], 0, 0, 0);
            }
            if (it + 3 < 9) LW(rev ? (8 - (it + 3)) : (it + 3), rb);
        }
        __builtin_amdgcn_s_setprio(0);

        // stage boundary — skipped after the last stage (no DMA in flight; the
        // epilogue never reads xa, and tb is per-wave)
        if (s + 1 < ns) {
            asm volatile("s_waitcnt vmcnt(0)" ::: "memory");
            __builtin_amdgcn_s_barrier();
            asm volatile("" ::: "memory");
        }
    }

    // epilogue, interp A (col=o, row=m — certified). tb per-wave: lgkmcnt only.
    const int o4 = lane >> 2;
    const int mc = lane & 3;
    float* tbw = tb[wv];
    const size_t plane = (size_t)d0 * 24 + d1;
    #pragma unroll
    for (int t = 0; t < 9; ++t) {
        #pragma unroll
        for (int nt = 0; nt < 2; ++nt) {
            asm volatile("" ::: "memory");
            *(f32x4*)&tbw[n * 20 + q * 4] = acc[t][nt];   // tb[o=n][m=q*4+r]
            asm volatile("s_waitcnt lgkmcnt(0)" ::: "memory");
            f32x4 vv = *(const f32x4*)&tbw[o4 * 20 + mc * 4];
            const int o = (og * 2 + nt) * 16 + o4;
            vv += bias[o];
            size_t off = ((size_t)(b * 64 + o) * 576 + plane) * 576
                       + (size_t)((mg * 9 + t) * 16 + mc * 4);
            __builtin_nontemporal_store(vv, (f32x4*)(out + off));
        }
    }
}

// ---- fallback (round-6 verified kernel, 2-term; used only if ws_size small) ----
__global__ __launch_bounds__(256, 1)
void conv4d_kernel(const float* __restrict__ x, const unsigned short* __restrict__ w2,
                   const float* __restrict__ bias, float* __restrict__ out) {
    __shared__ __align__(16) unsigned short xsh[27232];
    __shared__ __align__(16) float tb[4][320];

    const int tid  = threadIdx.x;
    const int lane = tid & 63;
    const int wv   = tid >> 6;
    const int n    = lane & 15;
    const int q    = lane >> 4;

    int bid = blockIdx.x;
    bid = (bid & 7) * 144 + (bid >> 3);
    const int d1 = bid % 24;
    const int d0 = (bid / 24) % 24;
    const int b  = bid / 576;

    for (int e = tid * 8; e < 27232; e += 2048) *(us8*)&xsh[e] = (us8)0;

    int abase[9];
    #pragma unroll
    for (int t = 0; t < 9; ++t) {
        int mflat = (wv * 9 + t) * 16 + n;
        int d2o = mflat / 24;
        int d3o = mflat - d2o * 24;
        abase[t] = d2o * RS + d3o * D3S + q * 8;
    }

    f32x4 acc[9][4];
    #pragma unroll
    for (int t = 0; t < 9; ++t)
        #pragma unroll
        for (int nt = 0; nt < 4; ++nt)
            acc[t][nt] = (f32x4)0.0f;

    const float* xb_b = x + (size_t)b * 10616832;
    const int cbase = wv * 8;
    const int k1lo = (d1 == 0) ? 1 : 0;
    const int k1hi = (d1 == 23) ? 1 : 2;
    const int nk = k1hi - k1lo + 1;
    const int ns = 3 * nk;

    f32x4 v[3][8];
    float mskC[8], mskN[8];
    {
        const int d1in = d1 + k1lo - 1;
        int off0[8];
        #pragma unroll
        for (int cc = 0; cc < 8; ++cc) {
            int r  = d0 * 32 + cbase + cc;
            int ci = r / 26;
            int pf = r - ci * 26 - 1;
            bool valid = ((unsigned)pf < 24u);
            off0[cc] = valid ? (ci * 331776 + pf * 13824 + d1in * 576) : 0;
            mskC[cc] = valid ? 1.0f : 0.0f;
        }
        #pragma unroll
        for (int jj = 0; jj < 3; ++jj) {
            int f4 = lane + 64 * jj;
            if (f4 < 144) {
                int d2  = f4 / 6;
                int d3c = f4 - d2 * 6;
                int pos = d2 * 24 + d3c * 4;
                #pragma unroll
                for (int cc = 0; cc < 8; ++cc)
                    v[jj][cc] = *(const f32x4*)(xb_b + off0[cc] + pos);
            }
        }
    }

    for (int s = 0; s < ns; ++s) {
        #pragma unroll
        for (int jj = 0; jj < 3; ++jj) {
            int f4 = lane + 64 * jj;
            if (f4 < 144) {
                int d2  = f4 / 6;
                int d3c = f4 - d2 * 6;
                const int le = (d2 + 1) * RS + (d3c * 4 + 1) * D3S + cbase;
                #pragma unroll
                for (int k = 0; k < 4; ++k) {
                    us8 hv;
                    #pragma unroll
                    for (int cc = 0; cc < 8; ++cc)
                        hv[cc] = f2bf(v[jj][cc][k] * mskC[cc]);
                    *(us8*)&xsh[le + k * D3S] = hv;
                }
            }
        }
        if (s + 1 < ns) {
            const int sn   = s + 1;
            const int i_n  = sn / nk;
            const int k1_n = k1lo + (sn - i_n * nk);
            const int d1in = d1 + k1_n - 1;
            int offn[8];
            #pragma unroll
            for (int cc = 0; cc < 8; ++cc) {
                int r  = (d0 + i_n) * 32 + cbase + cc;
                int ci = r / 26;
                int pf = r - ci * 26 - 1;
                bool valid = ((unsigned)pf < 24u);
                offn[cc] = valid ? (ci * 331776 + pf * 13824 + d1in * 576) : 0;
                mskN[cc] = valid ? 1.0f : 0.0f;
            }
            #pragma unroll
            for (int jj = 0; jj < 3; ++jj) {
                int f4 = lane + 64 * jj;
                if (f4 < 144) {
                    int d2  = f4 / 6;
                    int d3c = f4 - d2 * 6;
                    int pos = d2 * 24 + d3c * 4;
                    #pragma unroll
                    for (int cc = 0; cc < 8; ++cc)
                        v[jj][cc] = *(const f32x4*)(xb_b + offn[cc] + pos);
                }
            }
            #pragma unroll
            for (int cc = 0; cc < 8; ++cc) mskC[cc] = mskN[cc];
        }
        asm volatile("s_waitcnt lgkmcnt(0)" ::: "memory");
        __builtin_amdgcn_s_barrier();
        asm volatile("" ::: "memory");

        const int ik  = s / nk;
        const int k1c = k1lo + (s - ik * nk);
        const unsigned short* wsliceH = w2 + (size_t)((ik * 3 + k1c) * 9) * 2048;
        const unsigned short* wsliceL = wsliceH + WELEMS;
        __builtin_amdgcn_s_setprio(1);
        #pragma unroll
        for (int k2 = 0; k2 < 3; ++k2) {
            #pragma unroll
            for (int k3 = 0; k3 < 3; ++k3) {
                const int tap = k2 * 3 + k3;
                bf16x8 bh[4], bl[4];
                #pragma unroll
                for (int nt = 0; nt < 4; ++nt) {
                    const int wo = (tap * 64 + nt * 16 + n) * 32 + q * 8;
                    bh[nt] = __builtin_bit_cast(bf16x8, *(const us8*)(wsliceH + wo));
                    bl[nt] = __builtin_bit_cast(bf16x8, *(const us8*)(wsliceL + wo));
                }
                const int toff = k2 * RS + k3 * D3S;
                #pragma unroll
                for (int t = 0; t < 9; ++t) {
                    const bf16x8 ah = __builtin_bit_cast(bf16x8, *(const us8*)(&xsh[abase[t] + toff]));
                    #pragma unroll
                    for (int nt = 0; nt < 4; ++nt) {
                        acc[t][nt] = __builtin_amdgcn_mfma_f32_16x16x32_bf16(ah, bh[nt], acc[t][nt], 0, 0, 0);
                        acc[t][nt] = __builtin_amdgcn_mfma_f32_16x16x32_bf16(ah, bl[nt], acc[t][nt], 0, 0, 0);
                    }
                }
            }
        }
        __builtin_amdgcn_s_setprio(0);
        asm volatile("" ::: "memory");
        __builtin_amdgcn_s_barrier();
        asm volatile("" ::: "memory");
    }

    const int o4 = lane >> 2;
    const int mc = lane & 3;
    float* tbw = tb[wv];
    const size_t plane = (size_t)d0 * 24 + d1;
    #pragma unroll
    for (int t = 0; t < 9; ++t) {
        #pragma unroll
        for (int nt = 0; nt < 4; ++nt) {
            asm volatile("" ::: "memory");
            *(f32x4*)&tbw[n * 20 + q * 4] = acc[t][nt];
            asm volatile("s_waitcnt lgkmcnt(0)" ::: "memory");
            f32x4 vv = *(const f32x4*)&tbw[o4 * 20 + mc * 4];
            const int o = nt * 16 + o4;
            vv += bias[o];
            size_t off = ((size_t)(b * 64 + o) * 576 + plane) * 576
                       + (size_t)((wv * 9 + t) * 16 + mc * 4);
            __builtin_nontemporal_store(vv, (f32x4*)(out + off));
        }
    }
}

extern "C" void kernel_launch(void* const* d_in, const int* in_sizes, int n_in,
                              void* d_out, int out_size, void* d_ws, size_t ws_size,
                              hipStream_t stream) {
    const float* x    = (const float*)d_in[0];
    const float* w    = (const float*)d_in[1];
    const float* bias = (const float*)d_in[2];
    float* out        = (float*)d_out;
    unsigned short* w2 = (unsigned short*)d_ws;

    if (ws_size >= W2_BYTES + X2_BYTES) {
        unsigned short* x2 = (unsigned short*)((char*)d_ws + W2_BYTES);
        hipLaunchKernelGGL(prep_kernel, dim3(648 + 1248), dim3(256), 0, stream,
                           x, w, w2, x2);
        hipLaunchKernelGGL(conv4d_dma_kernel, dim3(1152), dim3(512), 0, stream,
                           x2, w2, bias, out);
    } else {
        hipLaunchKernelGGL(wconv_kernel, dim3(648), dim3(256), 0, stream, w, w2);
        hipLaunchKernelGGL(conv4d_kernel, dim3(1152), dim3(256), 0, stream,
                           x, w2, bias, out);
    }
}